// Round 1
// baseline (51.189 us; speedup 1.0000x reference)
//
#include <hip/hip_runtime.h>
#include <math.h>

#define NVOX 16384
#define NRAYS 2048
#define CAP 2048            // hit-list capacity per ray (expected ~17 hits)
#define BLK 256
#define STOPT 0.01f
#define FARP 100.0f

__global__ __launch_bounds__(BLK) void voxel_raster_kernel(
    const float* __restrict__ pos,   // (NVOX,3)
    const float* __restrict__ siz,   // (NVOX,)
    const float* __restrict__ den,   // (NVOX,)
    const float* __restrict__ col,   // (NVOX,3)
    const float* __restrict__ rob,   // (NRAYS,3)
    const float* __restrict__ rdb,   // (NRAYS,3)
    float* __restrict__ out)         // rgb[NRAYS*3] | depth[NRAYS] | weights[NRAYS]
{
    __shared__ float s_key[CAP];   // t_near
    __shared__ float s_op[CAP];    // opacity
    __shared__ int   s_cid[CAP];   // voxel index (for color)
    __shared__ int   s_cnt;

    const int ray = blockIdx.x;
    const int tid = threadIdx.x;
    if (tid == 0) s_cnt = 0;
    __syncthreads();

    const float ox = rob[ray * 3 + 0], oy = rob[ray * 3 + 1], oz = rob[ray * 3 + 2];
    const float dx = rdb[ray * 3 + 0], dy = rdb[ray * 3 + 1], dz = rdb[ray * 3 + 2];
    const float ix = 1.0f / dx, iy = 1.0f / dy, iz = 1.0f / dz;

    // Phase 1: slab test all voxels, collect hits into LDS
    for (int v = tid; v < NVOX; v += BLK) {
        const float px = pos[v * 3 + 0];
        const float py = pos[v * 3 + 1];
        const float pz = pos[v * 3 + 2];
        const float h  = siz[v] * 0.5f;

        const float t0x = (px - h - ox) * ix, t1x = (px + h - ox) * ix;
        const float t0y = (py - h - oy) * iy, t1y = (py + h - oy) * iy;
        const float t0z = (pz - h - oz) * iz, t1z = (pz + h - oz) * iz;

        const float tn = fmaxf(fmaxf(fminf(t0x, t1x), fminf(t0y, t1y)), fminf(t0z, t1z));
        const float tf = fminf(fminf(fmaxf(t0x, t1x), fmaxf(t0y, t1y)), fmaxf(t0z, t1z));

        if (tf > tn && tf > 0.0f) {
            const float delta = (tf - tn) * (1.0f / 7.0f);   // SAMPLES-1 = 7
            const float op = 1.0f - expf(-expf(den[v]) * delta);
            const int k = atomicAdd(&s_cnt, 1);
            if (k < CAP) {
                s_key[k] = tn;
                s_op[k]  = op;
                s_cid[k] = v;
            }
        }
    }
    __syncthreads();

    const int n = min(s_cnt, CAP);

    // pad to next power of two with +inf keys
    int p = 1;
    while (p < n) p <<= 1;
    for (int i = n + tid; i < p; i += BLK) s_key[i] = INFINITY;
    __syncthreads();

    // Phase 2: bitonic sort ascending by t_near
    for (int k = 2; k <= p; k <<= 1) {
        for (int j = k >> 1; j > 0; j >>= 1) {
            for (int i = tid; i < p; i += BLK) {
                const int l = i ^ j;
                if (l > i) {
                    const float a = s_key[i], b = s_key[l];
                    const bool up = ((i & k) == 0);
                    if ((a > b) == up) {
                        s_key[i] = b; s_key[l] = a;
                        const float oa = s_op[i];  s_op[i]  = s_op[l];  s_op[l]  = oa;
                        const int   ca = s_cid[i]; s_cid[i] = s_cid[l]; s_cid[l] = ca;
                    }
                }
            }
            __syncthreads();
        }
    }

    // Phase 3: serial front-to-back composite (hit counts are tiny)
    if (tid == 0) {
        float T = 1.0f;
        float r = 0.0f, g = 0.0f, b = 0.0f, dep = 0.0f, ws = 0.0f;
        for (int i = 0; i < n; ++i) {
            if (T < STOPT) break;           // all further w are exactly 0
            const float op = s_op[i];
            const float w  = T * op;
            const int   c  = s_cid[i];
            r   += w * col[c * 3 + 0];
            g   += w * col[c * 3 + 1];
            b   += w * col[c * 3 + 2];
            dep += w * s_key[i];
            ws  += w;
            T   *= (1.0f - op);
        }
        out[ray * 3 + 0] = r;
        out[ray * 3 + 1] = g;
        out[ray * 3 + 2] = b;
        out[NRAYS * 3 + ray] = (n > 0) ? dep : FARP;
        out[NRAYS * 4 + ray] = ws;
    }
}

extern "C" void kernel_launch(void* const* d_in, const int* in_sizes, int n_in,
                              void* d_out, int out_size, void* d_ws, size_t ws_size,
                              hipStream_t stream) {
    const float* pos = (const float*)d_in[0];
    const float* siz = (const float*)d_in[1];
    const float* den = (const float*)d_in[2];
    const float* col = (const float*)d_in[3];
    const float* rob = (const float*)d_in[4];
    const float* rdb = (const float*)d_in[5];
    float* out = (float*)d_out;

    voxel_raster_kernel<<<NRAYS, BLK, 0, stream>>>(pos, siz, den, col, rob, rdb, out);
}

// Round 2
// 40.322 us; speedup vs baseline: 1.2695x; 1.2695x over previous
//
#include <hip/hip_runtime.h>
#include <math.h>

#define NVOX 16384
#define NRAYS 2048
#define CAP 256             // hit-list capacity per ray (expected ~15 hits, 17-sigma margin)
#define BLK 256
#define RPB 2               // rays per block
#define STOPT 0.01f
#define FARP 100.0f

// Pre-pass: pack (px,py,pz,half) into float4, precompute exp(density).
__global__ __launch_bounds__(256) void pack_kernel(
    const float* __restrict__ pos, const float* __restrict__ siz,
    const float* __restrict__ den, float4* __restrict__ box,
    float* __restrict__ eden)
{
    const int v = blockIdx.x * 256 + threadIdx.x;
    if (v < NVOX) {
        float4 b;
        b.x = pos[v * 3 + 0];
        b.y = pos[v * 3 + 1];
        b.z = pos[v * 3 + 2];
        b.w = siz[v] * 0.5f;
        box[v] = b;
        eden[v] = expf(den[v]);
    }
}

template<bool PACKED>
__global__ __launch_bounds__(BLK) void raster_kernel(
    const float4* __restrict__ box, const float* __restrict__ eden,
    const float*  __restrict__ pos, const float* __restrict__ siz,
    const float*  __restrict__ den, const float* __restrict__ col,
    const float*  __restrict__ rob, const float* __restrict__ rdb,
    float* __restrict__ out)
{
    __shared__ float s_key[RPB][CAP];
    __shared__ float s_op [RPB][CAP];
    __shared__ int   s_cid[RPB][CAP];
    __shared__ int   s_cnt[RPB];

    const int tid  = threadIdx.x;
    const int ray0 = blockIdx.x * RPB;
    if (tid < RPB) s_cnt[tid] = 0;
    __syncthreads();

    // per-ray constants (uniform across block; cheap)
    float ivx[RPB], ivy[RPB], ivz[RPB], ofx[RPB], ofy[RPB], ofz[RPB];
#pragma unroll
    for (int r = 0; r < RPB; ++r) {
        const int ray = ray0 + r;
        const float ox = rob[ray * 3 + 0], oy = rob[ray * 3 + 1], oz = rob[ray * 3 + 2];
        const float dx = rdb[ray * 3 + 0], dy = rdb[ray * 3 + 1], dz = rdb[ray * 3 + 2];
        ivx[r] = 1.0f / dx; ivy[r] = 1.0f / dy; ivz[r] = 1.0f / dz;
        ofx[r] = -ox * ivx[r]; ofy[r] = -oy * ivy[r]; ofz[r] = -oz * ivz[r];
    }

    // Phase 1: slab-test every voxel against RPB rays; push hits to LDS
    for (int v = tid; v < NVOX; v += BLK) {
        float px, py, pz, h;
        if constexpr (PACKED) {
            const float4 b = box[v];
            px = b.x; py = b.y; pz = b.z; h = b.w;
        } else {
            px = pos[v * 3 + 0]; py = pos[v * 3 + 1]; pz = pos[v * 3 + 2];
            h = siz[v] * 0.5f;
        }
        const float bnx = px - h, bxx = px + h;
        const float bny = py - h, bxy = py + h;
        const float bnz = pz - h, bxz = pz + h;
#pragma unroll
        for (int r = 0; r < RPB; ++r) {
            const float t0x = fmaf(bnx, ivx[r], ofx[r]);
            const float t1x = fmaf(bxx, ivx[r], ofx[r]);
            const float t0y = fmaf(bny, ivy[r], ofy[r]);
            const float t1y = fmaf(bxy, ivy[r], ofy[r]);
            const float t0z = fmaf(bnz, ivz[r], ofz[r]);
            const float t1z = fmaf(bxz, ivz[r], ofz[r]);
            const float tn = fmaxf(fmaxf(fminf(t0x, t1x), fminf(t0y, t1y)), fminf(t0z, t1z));
            const float tf = fminf(fminf(fmaxf(t0x, t1x), fmaxf(t0y, t1y)), fmaxf(t0z, t1z));
            if (tf > tn && tf > 0.0f) {
                const float ed = PACKED ? eden[v] : expf(den[v]);
                const float op = 1.0f - expf(-ed * (tf - tn) * (1.0f / 7.0f));
                const int k = atomicAdd(&s_cnt[r], 1);
                if (k < CAP) { s_key[r][k] = tn; s_op[r][k] = op; s_cid[r][k] = v; }
            }
        }
    }
    __syncthreads();

    // Phase 2+3: wave w composites ray ray0+w via O(n^2) exclusive-product
    // (exactly the reference semantics: w_i = T_excl_i*op_i if T_excl_i >= STOP_T)
    const int wv = tid >> 6, lane = tid & 63;
    if (wv < RPB) {
        const int n = min(s_cnt[wv], CAP);
        float ar = 0.f, ag = 0.f, ab = 0.f, ad = 0.f, aw = 0.f;
        for (int i = lane; i < n; i += 64) {
            const float ti = s_key[wv][i], oi = s_op[wv][i];
            float T = 1.0f;
            for (int j = 0; j < n; ++j) {
                const float tj = s_key[wv][j];
                const float oj = s_op[wv][j];
                T *= (tj < ti) ? (1.0f - oj) : 1.0f;   // LDS broadcast, no conflict
            }
            const float w = (T >= STOPT) ? T * oi : 0.0f;
            const int c = s_cid[wv][i];
            ar += w * col[c * 3 + 0];
            ag += w * col[c * 3 + 1];
            ab += w * col[c * 3 + 2];
            ad += w * ti;
            aw += w;
        }
#pragma unroll
        for (int off = 32; off > 0; off >>= 1) {
            ar += __shfl_down(ar, off);
            ag += __shfl_down(ag, off);
            ab += __shfl_down(ab, off);
            ad += __shfl_down(ad, off);
            aw += __shfl_down(aw, off);
        }
        if (lane == 0) {
            const int ray = ray0 + wv;
            out[ray * 3 + 0] = ar;
            out[ray * 3 + 1] = ag;
            out[ray * 3 + 2] = ab;
            out[NRAYS * 3 + ray] = (n > 0) ? ad : FARP;
            out[NRAYS * 4 + ray] = aw;
        }
    }
}

extern "C" void kernel_launch(void* const* d_in, const int* in_sizes, int n_in,
                              void* d_out, int out_size, void* d_ws, size_t ws_size,
                              hipStream_t stream) {
    const float* pos = (const float*)d_in[0];
    const float* siz = (const float*)d_in[1];
    const float* den = (const float*)d_in[2];
    const float* col = (const float*)d_in[3];
    const float* rob = (const float*)d_in[4];
    const float* rdb = (const float*)d_in[5];
    float* out = (float*)d_out;

    const size_t need = (size_t)NVOX * sizeof(float4) + (size_t)NVOX * sizeof(float);
    if (ws_size >= need) {
        float4* box  = (float4*)d_ws;
        float*  eden = (float*)((char*)d_ws + (size_t)NVOX * sizeof(float4));
        pack_kernel<<<NVOX / 256, 256, 0, stream>>>(pos, siz, den, box, eden);
        raster_kernel<true><<<NRAYS / RPB, BLK, 0, stream>>>(box, eden, pos, siz, den, col, rob, rdb, out);
    } else {
        raster_kernel<false><<<NRAYS / RPB, BLK, 0, stream>>>(nullptr, nullptr, pos, siz, den, col, rob, rdb, out);
    }
}

// Round 3
// 35.721 us; speedup vs baseline: 1.4330x; 1.1288x over previous
//
#include <hip/hip_runtime.h>
#include <math.h>

#define NVOX 16384
#define NRAYS 2048
#define CAP 256             // hit-list capacity per ray (expected ~15 hits)
#define BLK 256
#define RPB 4               // rays per block (one wave per ray in phase 2)
#define STOPT 0.01f
#define FARP 100.0f

__global__ __launch_bounds__(BLK) void raster_kernel(
    const float* __restrict__ pos,   // (NVOX,3)
    const float* __restrict__ siz,   // (NVOX,)
    const float* __restrict__ den,   // (NVOX,)
    const float* __restrict__ col,   // (NVOX,3)
    const float* __restrict__ rob,   // (NRAYS,3)
    const float* __restrict__ rdb,   // (NRAYS,3)
    float* __restrict__ out)         // rgb[NRAYS*3] | depth[NRAYS] | weights[NRAYS]
{
    __shared__ float s_key[RPB][CAP];
    __shared__ float s_op [RPB][CAP];
    __shared__ int   s_cid[RPB][CAP];
    __shared__ int   s_cnt[RPB];

    const int tid  = threadIdx.x;
    const int ray0 = blockIdx.x * RPB;
    if (tid < RPB) s_cnt[tid] = 0;
    __syncthreads();

    // per-ray constants (block-uniform addresses -> scalar loads)
    float ivx[RPB], ivy[RPB], ivz[RPB], ofx[RPB], ofy[RPB], ofz[RPB];
#pragma unroll
    for (int r = 0; r < RPB; ++r) {
        const int ray = ray0 + r;
        const float ox = rob[ray * 3 + 0], oy = rob[ray * 3 + 1], oz = rob[ray * 3 + 2];
        const float dx = rdb[ray * 3 + 0], dy = rdb[ray * 3 + 1], dz = rdb[ray * 3 + 2];
        ivx[r] = 1.0f / dx;      ivy[r] = 1.0f / dy;      ivz[r] = 1.0f / dz;
        ofx[r] = -ox * ivx[r];   ofy[r] = -oy * ivy[r];   ofz[r] = -oz * ivz[r];
    }

    // Phase 1: slab-test every voxel against RPB rays; push hits to LDS
#pragma unroll 2
    for (int v = tid; v < NVOX; v += BLK) {
        const float px = pos[v * 3 + 0];
        const float py = pos[v * 3 + 1];
        const float pz = pos[v * 3 + 2];
        const float h  = siz[v] * 0.5f;
        const float bnx = px - h, bxx = px + h;
        const float bny = py - h, bxy = py + h;
        const float bnz = pz - h, bxz = pz + h;
#pragma unroll
        for (int r = 0; r < RPB; ++r) {
            const float t0x = fmaf(bnx, ivx[r], ofx[r]);
            const float t1x = fmaf(bxx, ivx[r], ofx[r]);
            const float t0y = fmaf(bny, ivy[r], ofy[r]);
            const float t1y = fmaf(bxy, ivy[r], ofy[r]);
            const float t0z = fmaf(bnz, ivz[r], ofz[r]);
            const float t1z = fmaf(bxz, ivz[r], ofz[r]);
            const float tn = fmaxf(fmaxf(fminf(t0x, t1x), fminf(t0y, t1y)), fminf(t0z, t1z));
            const float tf = fminf(fminf(fmaxf(t0x, t1x), fmaxf(t0y, t1y)), fmaxf(t0z, t1z));
            if (tf > tn && tf > 0.0f) {
                const float op = 1.0f - expf(-expf(den[v]) * (tf - tn) * (1.0f / 7.0f));
                const int k = atomicAdd(&s_cnt[r], 1);
                if (k < CAP) { s_key[r][k] = tn; s_op[r][k] = op; s_cid[r][k] = v; }
            }
        }
    }
    __syncthreads();

    // Phase 2: wave wv composites ray ray0+wv via O(n^2) exclusive-product
    // (reference semantics: w_i = T_excl_i*op_i if T_excl_i >= STOP_T, order-free)
    const int wv = tid >> 6, lane = tid & 63;
    if (wv < RPB) {
        const int n = min(s_cnt[wv], CAP);
        float ar = 0.f, ag = 0.f, ab = 0.f, ad = 0.f, aw = 0.f;
        for (int i = lane; i < n; i += 64) {
            const float ti = s_key[wv][i], oi = s_op[wv][i];
            float T = 1.0f;
            for (int j = 0; j < n; ++j) {
                const float tj = s_key[wv][j];
                const float oj = s_op[wv][j];
                T *= (tj < ti) ? (1.0f - oj) : 1.0f;   // LDS broadcast reads
            }
            const float w = (T >= STOPT) ? T * oi : 0.0f;
            const int c = s_cid[wv][i];
            ar += w * col[c * 3 + 0];
            ag += w * col[c * 3 + 1];
            ab += w * col[c * 3 + 2];
            ad += w * ti;
            aw += w;
        }
#pragma unroll
        for (int off = 32; off > 0; off >>= 1) {
            ar += __shfl_down(ar, off);
            ag += __shfl_down(ag, off);
            ab += __shfl_down(ab, off);
            ad += __shfl_down(ad, off);
            aw += __shfl_down(aw, off);
        }
        if (lane == 0) {
            const int ray = ray0 + wv;
            out[ray * 3 + 0] = ar;
            out[ray * 3 + 1] = ag;
            out[ray * 3 + 2] = ab;
            out[NRAYS * 3 + ray] = (n > 0) ? ad : FARP;
            out[NRAYS * 4 + ray] = aw;
        }
    }
}

extern "C" void kernel_launch(void* const* d_in, const int* in_sizes, int n_in,
                              void* d_out, int out_size, void* d_ws, size_t ws_size,
                              hipStream_t stream) {
    const float* pos = (const float*)d_in[0];
    const float* siz = (const float*)d_in[1];
    const float* den = (const float*)d_in[2];
    const float* col = (const float*)d_in[3];
    const float* rob = (const float*)d_in[4];
    const float* rdb = (const float*)d_in[5];
    float* out = (float*)d_out;

    raster_kernel<<<NRAYS / RPB, BLK, 0, stream>>>(pos, siz, den, col, rob, rdb, out);
}

// Round 4
// 27.435 us; speedup vs baseline: 1.8658x; 1.3020x over previous
//
#include <hip/hip_runtime.h>
#include <math.h>

#define NVOX 16384
#define NRAYS 2048
#define CAP 256             // hit-list capacity per ray (expected ~15 hits)
#define BLK 1024            // 16 waves/block, 2 blocks/CU -> 32 waves/CU (100% occ)
#define RPB 4               // rays per block (one wave per ray in phase 2)
#define STOPT 0.01f
#define FARP 100.0f

__global__ __launch_bounds__(BLK) void raster_kernel(
    const float* __restrict__ pos,   // (NVOX,3)
    const float* __restrict__ siz,   // (NVOX,)
    const float* __restrict__ den,   // (NVOX,)
    const float* __restrict__ col,   // (NVOX,3)
    const float* __restrict__ rob,   // (NRAYS,3)
    const float* __restrict__ rdb,   // (NRAYS,3)
    float* __restrict__ out)         // rgb[NRAYS*3] | depth[NRAYS] | weights[NRAYS]
{
    __shared__ float s_key[RPB][CAP];
    __shared__ float s_op [RPB][CAP];
    __shared__ int   s_cid[RPB][CAP];
    __shared__ int   s_cnt[RPB];

    const int tid  = threadIdx.x;
    const int ray0 = blockIdx.x * RPB;
    if (tid < RPB) s_cnt[tid] = 0;
    __syncthreads();

    // per-ray constants (block-uniform addresses -> scalar loads)
    float ivx[RPB], ivy[RPB], ivz[RPB], ofx[RPB], ofy[RPB], ofz[RPB];
#pragma unroll
    for (int r = 0; r < RPB; ++r) {
        const int ray = ray0 + r;
        const float ox = rob[ray * 3 + 0], oy = rob[ray * 3 + 1], oz = rob[ray * 3 + 2];
        const float dx = rdb[ray * 3 + 0], dy = rdb[ray * 3 + 1], dz = rdb[ray * 3 + 2];
        ivx[r] = 1.0f / dx;      ivy[r] = 1.0f / dy;      ivz[r] = 1.0f / dz;
        ofx[r] = -ox * ivx[r];   ofy[r] = -oy * ivy[r];   ofz[r] = -oz * ivz[r];
    }

    // Phase 1: slab-test every voxel against RPB rays; push hits to LDS
#pragma unroll 4
    for (int v = tid; v < NVOX; v += BLK) {
        const float px = pos[v * 3 + 0];
        const float py = pos[v * 3 + 1];
        const float pz = pos[v * 3 + 2];
        const float h  = siz[v] * 0.5f;
        const float bnx = px - h, bxx = px + h;
        const float bny = py - h, bxy = py + h;
        const float bnz = pz - h, bxz = pz + h;
#pragma unroll
        for (int r = 0; r < RPB; ++r) {
            const float t0x = fmaf(bnx, ivx[r], ofx[r]);
            const float t1x = fmaf(bxx, ivx[r], ofx[r]);
            const float t0y = fmaf(bny, ivy[r], ofy[r]);
            const float t1y = fmaf(bxy, ivy[r], ofy[r]);
            const float t0z = fmaf(bnz, ivz[r], ofz[r]);
            const float t1z = fmaf(bxz, ivz[r], ofz[r]);
            const float tn = fmaxf(fmaxf(fminf(t0x, t1x), fminf(t0y, t1y)), fminf(t0z, t1z));
            const float tf = fminf(fminf(fmaxf(t0x, t1x), fmaxf(t0y, t1y)), fmaxf(t0z, t1z));
            if (tf > tn && tf > 0.0f) {
                const float op = 1.0f - expf(-expf(den[v]) * (tf - tn) * (1.0f / 7.0f));
                const int k = atomicAdd(&s_cnt[r], 1);
                if (k < CAP) { s_key[r][k] = tn; s_op[r][k] = op; s_cid[r][k] = v; }
            }
        }
    }
    __syncthreads();

    // Phase 2: wave wv composites ray ray0+wv via O(n^2) exclusive-product
    // (reference semantics: w_i = T_excl_i*op_i if T_excl_i >= STOP_T, order-free)
    const int wv = tid >> 6, lane = tid & 63;
    if (wv < RPB) {
        const int n = min(s_cnt[wv], CAP);
        float ar = 0.f, ag = 0.f, ab = 0.f, ad = 0.f, aw = 0.f;
        for (int i = lane; i < n; i += 64) {
            const float ti = s_key[wv][i], oi = s_op[wv][i];
            float T = 1.0f;
            for (int j = 0; j < n; ++j) {
                const float tj = s_key[wv][j];
                const float oj = s_op[wv][j];
                T *= (tj < ti) ? (1.0f - oj) : 1.0f;   // LDS broadcast reads
            }
            const float w = (T >= STOPT) ? T * oi : 0.0f;
            const int c = s_cid[wv][i];
            ar += w * col[c * 3 + 0];
            ag += w * col[c * 3 + 1];
            ab += w * col[c * 3 + 2];
            ad += w * ti;
            aw += w;
        }
#pragma unroll
        for (int off = 32; off > 0; off >>= 1) {
            ar += __shfl_down(ar, off);
            ag += __shfl_down(ag, off);
            ab += __shfl_down(ab, off);
            ad += __shfl_down(ad, off);
            aw += __shfl_down(aw, off);
        }
        if (lane == 0) {
            const int ray = ray0 + wv;
            out[ray * 3 + 0] = ar;
            out[ray * 3 + 1] = ab * 0.0f + ag * 0.0f + ar * 0.0f + ag;  // placeholder avoided below
        }
        if (lane == 0) {
            const int ray = ray0 + wv;
            out[ray * 3 + 0] = ar;
            out[ray * 3 + 1] = ag;
            out[ray * 3 + 2] = ab;
            out[NRAYS * 3 + ray] = (n > 0) ? ad : FARP;
            out[NRAYS * 4 + ray] = aw;
        }
    }
}

extern "C" void kernel_launch(void* const* d_in, const int* in_sizes, int n_in,
                              void* d_out, int out_size, void* d_ws, size_t ws_size,
                              hipStream_t stream) {
    const float* pos = (const float*)d_in[0];
    const float* siz = (const float*)d_in[1];
    const float* den = (const float*)d_in[2];
    const float* col = (const float*)d_in[3];
    const float* rob = (const float*)d_in[4];
    const float* rdb = (const float*)d_in[5];
    float* out = (float*)d_out;

    raster_kernel<<<NRAYS / RPB, BLK, 0, stream>>>(pos, siz, den, col, rob, rdb, out);
}